// Round 1
// baseline (657.941 us; speedup 1.0000x reference)
//
#include <hip/hip_runtime.h>
#include <stdint.h>

// Instant-NGP HashGrid forward, MI355X.
// N=2^20 points, 16 levels, F=2 feats, T=65536 entries/level.
// Levels 0..2 dense (res^3 <= T), 3..15 spatially hashed.
// One thread per point; 16 levels fully unrolled; 8 float2 gathers/level;
// 32-float accumulator in registers; 8x float4 contiguous store per point.

#define NLVL 16
#define TS 65536
#define P2 2654435761u
#define P3 805459861u

__global__ __launch_bounds__(256) void hashgrid_fwd(
    const float* __restrict__ x,
    const float* __restrict__ table,
    float* __restrict__ out,
    int n)
{
    const int tid = blockIdx.x * 256 + threadIdx.x;
    if (tid >= n) return;

    const float px = x[3 * tid + 0];
    const float py = x[3 * tid + 1];
    const float pz = x[3 * tid + 2];

    // scale = 16*1.5^l - 1 (exact in double, cast to f32 like the reference);
    // res = ceil(scale)+1
    const float SCALES[NLVL] = {
        15.0f, 23.0f, 35.0f, 53.0f, 80.0f, 120.5f, 181.25f, 272.375f,
        409.0625f, 614.09375f, 921.640625f, 1382.9609375f,
        2074.94140625f, 3112.912109375f, 4669.8681640625f, 7005.30224609375f};
    const int RESO[NLVL] = {16, 24, 36, 54, 81, 122, 183, 274,
                            411, 616, 923, 1384, 2076, 3114, 4671, 7007};

    float acc[32];

#pragma unroll
    for (int l = 0; l < NLVL; ++l) {
        const float scale = SCALES[l];
        const float fx = px * scale + 0.5f;
        const float fy = py * scale + 0.5f;
        const float fz = pz * scale + 0.5f;
        const float gx = floorf(fx), gy = floorf(fy), gz = floorf(fz);
        const float wx = fx - gx, wy = fy - gy, wz = fz - gz;
        const int ix = (int)gx, iy = (int)gy, iz = (int)gz;

        const float2* tbl = ((const float2*)table) + (size_t)l * TS;

        float2 c0, c1, c2, c3, c4, c5, c6, c7;
        if (l < 3) {
            // dense: idx = x + y*R + z*R*R, coords clipped to [0, R-1]
            const int R = RESO[l];
            const int x0 = min(ix, R - 1), x1 = min(ix + 1, R - 1);
            const int y0 = min(iy, R - 1), y1 = min(iy + 1, R - 1);
            const int z0 = min(iz, R - 1), z1 = min(iz + 1, R - 1);
            const int y0R = y0 * R, y1R = y1 * R;
            const int z0R = z0 * R * R, z1R = z1 * R * R;
            c0 = tbl[x0 + y0R + z0R];  // (0,0,0)
            c1 = tbl[x0 + y0R + z1R];  // (0,0,1)
            c2 = tbl[x0 + y1R + z0R];  // (0,1,0)
            c3 = tbl[x0 + y1R + z1R];  // (0,1,1)
            c4 = tbl[x1 + y0R + z0R];  // (1,0,0)
            c5 = tbl[x1 + y0R + z1R];  // (1,0,1)
            c6 = tbl[x1 + y1R + z0R];  // (1,1,0)
            c7 = tbl[x1 + y1R + z1R];  // (1,1,1)
        } else {
            // spatial hash: (x*1 ^ y*P2 ^ z*P3) & (T-1), no clipping
            const uint32_t hx0 = (uint32_t)ix, hx1 = (uint32_t)(ix + 1);
            const uint32_t hy0 = (uint32_t)iy * P2, hy1 = (uint32_t)(iy + 1) * P2;
            const uint32_t hz0 = (uint32_t)iz * P3, hz1 = (uint32_t)(iz + 1) * P3;
            c0 = tbl[(hx0 ^ hy0 ^ hz0) & (TS - 1)];
            c1 = tbl[(hx0 ^ hy0 ^ hz1) & (TS - 1)];
            c2 = tbl[(hx0 ^ hy1 ^ hz0) & (TS - 1)];
            c3 = tbl[(hx0 ^ hy1 ^ hz1) & (TS - 1)];
            c4 = tbl[(hx1 ^ hy0 ^ hz0) & (TS - 1)];
            c5 = tbl[(hx1 ^ hy0 ^ hz1) & (TS - 1)];
            c6 = tbl[(hx1 ^ hy1 ^ hz0) & (TS - 1)];
            c7 = tbl[(hx1 ^ hy1 ^ hz1) & (TS - 1)];
        }

        const float ux = 1.0f - wx, uy = 1.0f - wy, uz = 1.0f - wz;
        const float w0 = ux * uy * uz;  // (0,0,0)
        const float w1 = ux * uy * wz;  // (0,0,1)
        const float w2 = ux * wy * uz;  // (0,1,0)
        const float w3 = ux * wy * wz;  // (0,1,1)
        const float w4 = wx * uy * uz;  // (1,0,0)
        const float w5 = wx * uy * wz;  // (1,0,1)
        const float w6 = wx * wy * uz;  // (1,1,0)
        const float w7 = wx * wy * wz;  // (1,1,1)

        float o0 = w0 * c0.x + w1 * c1.x + w2 * c2.x + w3 * c3.x +
                   w4 * c4.x + w5 * c5.x + w6 * c6.x + w7 * c7.x;
        float o1 = w0 * c0.y + w1 * c1.y + w2 * c2.y + w3 * c3.y +
                   w4 * c4.y + w5 * c5.y + w6 * c6.y + w7 * c7.y;

        acc[2 * l + 0] = o0;
        acc[2 * l + 1] = o1;
    }

    // each point's 32 outputs are contiguous & 128B-aligned -> 8x float4 store
    float4* op = (float4*)(out + (size_t)tid * 32);
#pragma unroll
    for (int i = 0; i < 8; ++i) {
        op[i] = make_float4(acc[4 * i + 0], acc[4 * i + 1],
                            acc[4 * i + 2], acc[4 * i + 3]);
    }
}

extern "C" void kernel_launch(void* const* d_in, const int* in_sizes, int n_in,
                              void* d_out, int out_size, void* d_ws, size_t ws_size,
                              hipStream_t stream) {
    const float* x = (const float*)d_in[0];     // [N,3] f32
    const float* table = (const float*)d_in[1]; // [16,65536,2] f32
    float* out = (float*)d_out;                 // [N,32] f32
    const int n = in_sizes[0] / 3;
    const int block = 256;
    const int grid = (n + block - 1) / block;
    hashgrid_fwd<<<grid, block, 0, stream>>>(x, table, out, n);
}

// Round 2
// 568.962 us; speedup vs baseline: 1.1564x; 1.1564x over previous
//
#include <hip/hip_runtime.h>
#include <stdint.h>

// Instant-NGP HashGrid forward, MI355X. TA-gather-bound kernel.
// R1: merge x-corner pairs into float4 gathers (dense: always; hashed: even-x
// lanes via h(x+1)=h(x)^1), LDS-transposed full-line output stores.

#define NLVL 16
#define TS 65536
#define P2 2654435761u
#define P3 805459861u

__device__ __forceinline__ float2 f4lo(float4 v) { return make_float2(v.x, v.y); }
__device__ __forceinline__ float2 f4hi(float4 v) { return make_float2(v.z, v.w); }

__global__ __launch_bounds__(256) void hashgrid_fwd(
    const float* __restrict__ x,
    const float* __restrict__ table,
    float* __restrict__ out,
    int n)
{
    const int tid0 = blockIdx.x * 256 + threadIdx.x;
    const int tid = min(tid0, n - 1);

    const float px = x[3 * tid + 0];
    const float py = x[3 * tid + 1];
    const float pz = x[3 * tid + 2];

    const float SCALES[NLVL] = {
        15.0f, 23.0f, 35.0f, 53.0f, 80.0f, 120.5f, 181.25f, 272.375f,
        409.0625f, 614.09375f, 921.640625f, 1382.9609375f,
        2074.94140625f, 3112.912109375f, 4669.8681640625f, 7005.30224609375f};
    const int RESO[NLVL] = {16, 24, 36, 54, 81, 122, 183, 274,
                            411, 616, 923, 1384, 2076, 3114, 4671, 7007};

    float acc[32];

#pragma unroll
    for (int l = 0; l < NLVL; ++l) {
        const float scale = SCALES[l];
        const float fx = px * scale + 0.5f;
        const float fy = py * scale + 0.5f;
        const float fz = pz * scale + 0.5f;
        const float gx = floorf(fx), gy = floorf(fy), gz = floorf(fz);
        const float wx = fx - gx, wy = fy - gy, wz = fz - gz;
        const int ix = (int)gx, iy = (int)gy, iz = (int)gz;

        const float2* tbl = ((const float2*)table) + (size_t)l * TS;

        // c0=(0,0,0) c1=(0,0,1) c2=(0,1,0) c3=(0,1,1)
        // c4=(1,0,0) c5=(1,0,1) c6=(1,1,0) c7=(1,1,1)   (x,y,z corner bits)
        float2 c0, c1, c2, c3, c4, c5, c6, c7;
        if (l < 3) {
            // dense: idx = x + y*R + z*R^2, coords clipped to [0,R-1].
            // x-pair (x0,x0+1) adjacent -> one float4 based at xb=min(x0,R-2):
            //   x0<=R-2: pair (x0,x0+1) -> lo=entry x0, hi=entry x0+1
            //   x0==R-1 (clip): pair (R-2,R-1) -> both corners = entry R-1 = hi
            const int R = RESO[l];
            const int x0 = min(ix, R - 1);
            const int y0 = min(iy, R - 1), y1 = min(iy + 1, R - 1);
            const int z0 = min(iz, R - 1), z1 = min(iz + 1, R - 1);
            const int xb = min(x0, R - 2);
            const bool hi0 = (x0 != xb);  // x0 clipped to R-1
            const int y0R = y0 * R, y1R = y1 * R;
            const int z0R = z0 * R * R, z1R = z1 * R * R;
            const float4 f00 = *(const float4*)(tbl + (xb + y0R + z0R));
            const float4 f01 = *(const float4*)(tbl + (xb + y0R + z1R));
            const float4 f10 = *(const float4*)(tbl + (xb + y1R + z0R));
            const float4 f11 = *(const float4*)(tbl + (xb + y1R + z1R));
            c0 = hi0 ? f4hi(f00) : f4lo(f00);  c4 = f4hi(f00);
            c1 = hi0 ? f4hi(f01) : f4lo(f01);  c5 = f4hi(f01);
            c2 = hi0 ? f4hi(f10) : f4lo(f10);  c6 = f4hi(f10);
            c3 = hi0 ? f4hi(f11) : f4lo(f11);  c7 = f4hi(f11);
        } else {
            // hashed: h = x ^ y*P2 ^ z*P3, idx = h & (T-1).
            // P2,P3 odd => for even x0: h(x0+1) = h(x0)^1 -> same aligned pair.
            // Always load the aligned pair (idx&~1, idx|1) as one float4;
            // odd-x lanes additionally load the 4 unrelated x+1 entries.
            const uint32_t bx = (uint32_t)ix;
            const uint32_t hy0 = (uint32_t)iy * P2, hy1 = hy0 + P2;
            const uint32_t hz0 = (uint32_t)iz * P3, hz1 = hz0 + P3;
            const uint32_t b00 = hy0 ^ hz0, b01 = hy0 ^ hz1;
            const uint32_t b10 = hy1 ^ hz0, b11 = hy1 ^ hz1;
            const uint32_t i00 = (bx ^ b00) & (TS - 1);
            const uint32_t i01 = (bx ^ b01) & (TS - 1);
            const uint32_t i10 = (bx ^ b10) & (TS - 1);
            const uint32_t i11 = (bx ^ b11) & (TS - 1);
            const float4* tbl4 = (const float4*)tbl;
            const float4 f00 = tbl4[i00 >> 1];
            const float4 f01 = tbl4[i01 >> 1];
            const float4 f10 = tbl4[i10 >> 1];
            const float4 f11 = tbl4[i11 >> 1];
            c0 = (i00 & 1) ? f4hi(f00) : f4lo(f00);
            c1 = (i01 & 1) ? f4hi(f01) : f4lo(f01);
            c2 = (i10 & 1) ? f4hi(f10) : f4lo(f10);
            c3 = (i11 & 1) ? f4hi(f11) : f4lo(f11);
            if ((ix & 1) == 0) {
                // even x0: entry idx^1 is the x+1 corner (other float4 half)
                c4 = (i00 & 1) ? f4lo(f00) : f4hi(f00);
                c5 = (i01 & 1) ? f4lo(f01) : f4hi(f01);
                c6 = (i10 & 1) ? f4lo(f10) : f4hi(f10);
                c7 = (i11 & 1) ? f4lo(f11) : f4hi(f11);
            } else {
                const uint32_t bx1 = bx + 1;
                c4 = tbl[(bx1 ^ b00) & (TS - 1)];
                c5 = tbl[(bx1 ^ b01) & (TS - 1)];
                c6 = tbl[(bx1 ^ b10) & (TS - 1)];
                c7 = tbl[(bx1 ^ b11) & (TS - 1)];
            }
        }

        const float ux = 1.0f - wx, uy = 1.0f - wy, uz = 1.0f - wz;
        const float w0 = ux * uy * uz;
        const float w1 = ux * uy * wz;
        const float w2 = ux * wy * uz;
        const float w3 = ux * wy * wz;
        const float w4 = wx * uy * uz;
        const float w5 = wx * uy * wz;
        const float w6 = wx * wy * uz;
        const float w7 = wx * wy * wz;

        acc[2 * l + 0] = w0 * c0.x + w1 * c1.x + w2 * c2.x + w3 * c3.x +
                         w4 * c4.x + w5 * c5.x + w6 * c6.x + w7 * c7.x;
        acc[2 * l + 1] = w0 * c0.y + w1 * c1.y + w2 * c2.y + w3 * c3.y +
                         w4 * c4.y + w5 * c5.y + w6 * c6.y + w7 * c7.y;
    }

    // LDS-transposed epilogue: two passes of 128 points, stride-33 padding
    // (bank = (p + f) mod 32 across lanes -> 2-way max = free). Each store
    // instruction then covers 1 KiB contiguous -> full-line HBM writes.
    __shared__ float lds[128 * 33];
    const int half = threadIdx.x >> 7;   // which pass this thread's point is in
    const int tl = threadIdx.x & 127;
    float* outb = out + (size_t)blockIdx.x * (256 * 32);
    const long long lim = (long long)n * 32 - (long long)blockIdx.x * (256 * 32);

#pragma unroll
    for (int pass = 0; pass < 2; ++pass) {
        if (half == pass) {
#pragma unroll
            for (int j = 0; j < 32; ++j) lds[tl * 33 + j] = acc[j];
        }
        __syncthreads();
        float* o = outb + pass * (128 * 32);
        const long long plim = lim - pass * (128 * 32);
#pragma unroll
        for (int r = 0; r < 16; ++r) {
            const int g = r * 256 + threadIdx.x;   // 0..4095
            const int p = g >> 5, f = g & 31;
            if (g < plim) o[g] = lds[p * 33 + f];
        }
        __syncthreads();
    }
}

extern "C" void kernel_launch(void* const* d_in, const int* in_sizes, int n_in,
                              void* d_out, int out_size, void* d_ws, size_t ws_size,
                              hipStream_t stream) {
    const float* x = (const float*)d_in[0];     // [N,3] f32
    const float* table = (const float*)d_in[1]; // [16,65536,2] f32
    float* out = (float*)d_out;                 // [N,32] f32
    const int n = in_sizes[0] / 3;
    const int block = 256;
    const int grid = (n + block - 1) / block;
    hashgrid_fwd<<<grid, block, 0, stream>>>(x, table, out, n);
}

// Round 3
// 528.219 us; speedup vs baseline: 1.2456x; 1.0771x over previous
//
#include <hip/hip_runtime.h>
#include <stdint.h>

// Instant-NGP HashGrid forward, MI355X. TA-gather-bound.
// R2: per-level results written straight to a swizzled 32KB LDS tile
// (no acc[32] in regs), hashed levels as a rolled loop (unroll 2) ->
// VGPR ~<=102, 5 blocks/CU, ~20 waves/CU to hide gather latency.

#define NLVL 16
#define TS 65536
#define P2 2654435761u
#define P3 805459861u

__constant__ float C_SCALES[NLVL] = {
    15.0f, 23.0f, 35.0f, 53.0f, 80.0f, 120.5f, 181.25f, 272.375f,
    409.0625f, 614.09375f, 921.640625f, 1382.9609375f,
    2074.94140625f, 3112.912109375f, 4669.8681640625f, 7005.30224609375f};

__device__ __forceinline__ float2 f4lo(float4 v) { return make_float2(v.x, v.y); }
__device__ __forceinline__ float2 f4hi(float4 v) { return make_float2(v.z, v.w); }

// Swizzled LDS address: addr(p,f) = p*32 + (f ^ (p&31)).
// Write features (2l, 2l+1) for point p as an adjacent pair.
__device__ __forceinline__ void lds_put2(float* s_out, int p, int f2,
                                         float a, float b) {
    const int sw = p & 31;
    const int base = p * 32 + (f2 ^ (sw & 30));
    if (sw & 1) { s_out[base] = b; s_out[base + 1] = a; }
    else        { s_out[base] = a; s_out[base + 1] = b; }
}

__global__ __launch_bounds__(256, 5) void hashgrid_fwd(
    const float* __restrict__ x,
    const float* __restrict__ table,
    float* __restrict__ out,
    int n)
{
    __shared__ float s_out[256 * 32];  // 32 KiB, XOR-swizzled transpose tile

    const int tid0 = blockIdx.x * 256 + threadIdx.x;
    const int tid = min(tid0, n - 1);
    const int p = threadIdx.x;

    const float px = x[3 * tid + 0];
    const float py = x[3 * tid + 1];
    const float pz = x[3 * tid + 2];

    // ---- dense levels 0..2 (tables 32/110/373 KB -> L2-hot), unrolled ----
    {
        const int RESO[3] = {16, 24, 36};
        const float DSC[3] = {15.0f, 23.0f, 35.0f};
#pragma unroll
        for (int l = 0; l < 3; ++l) {
            const float scale = DSC[l];
            const float fx = px * scale + 0.5f;
            const float fy = py * scale + 0.5f;
            const float fz = pz * scale + 0.5f;
            const float gx = floorf(fx), gy = floorf(fy), gz = floorf(fz);
            const float wx = fx - gx, wy = fy - gy, wz = fz - gz;
            const int ix = (int)gx, iy = (int)gy, iz = (int)gz;

            const float2* tbl = ((const float2*)table) + (size_t)l * TS;
            const int R = RESO[l];
            const int x0 = min(ix, R - 1);
            const int y0 = min(iy, R - 1), y1 = min(iy + 1, R - 1);
            const int z0 = min(iz, R - 1), z1 = min(iz + 1, R - 1);
            const int xb = min(x0, R - 2);
            const bool hi0 = (x0 != xb);
            const int y0R = y0 * R, y1R = y1 * R;
            const int z0R = z0 * R * R, z1R = z1 * R * R;
            const float4 f00 = *(const float4*)(tbl + (xb + y0R + z0R));
            const float4 f01 = *(const float4*)(tbl + (xb + y0R + z1R));
            const float4 f10 = *(const float4*)(tbl + (xb + y1R + z0R));
            const float4 f11 = *(const float4*)(tbl + (xb + y1R + z1R));
            const float2 c0 = hi0 ? f4hi(f00) : f4lo(f00), c4 = f4hi(f00);
            const float2 c1 = hi0 ? f4hi(f01) : f4lo(f01), c5 = f4hi(f01);
            const float2 c2 = hi0 ? f4hi(f10) : f4lo(f10), c6 = f4hi(f10);
            const float2 c3 = hi0 ? f4hi(f11) : f4lo(f11), c7 = f4hi(f11);

            const float ux = 1.0f - wx, uy = 1.0f - wy, uz = 1.0f - wz;
            const float w0 = ux * uy * uz, w1 = ux * uy * wz;
            const float w2 = ux * wy * uz, w3 = ux * wy * wz;
            const float w4 = wx * uy * uz, w5 = wx * uy * wz;
            const float w6 = wx * wy * uz, w7 = wx * wy * wz;

            const float o0 = w0 * c0.x + w1 * c1.x + w2 * c2.x + w3 * c3.x +
                             w4 * c4.x + w5 * c5.x + w6 * c6.x + w7 * c7.x;
            const float o1 = w0 * c0.y + w1 * c1.y + w2 * c2.y + w3 * c3.y +
                             w4 * c4.y + w5 * c5.y + w6 * c6.y + w7 * c7.y;
            lds_put2(s_out, p, 2 * l, o0, o1);
        }
    }

    // ---- hashed levels 3..15: rolled loop, unroll 2 for ILP ----
#pragma unroll 2
    for (int l = 3; l < NLVL; ++l) {
        const float scale = C_SCALES[l];
        const float fx = px * scale + 0.5f;
        const float fy = py * scale + 0.5f;
        const float fz = pz * scale + 0.5f;
        const float gx = floorf(fx), gy = floorf(fy), gz = floorf(fz);
        const float wx = fx - gx, wy = fy - gy, wz = fz - gz;
        const int ix = (int)gx, iy = (int)gy, iz = (int)gz;

        const float2* tbl = ((const float2*)table) + (size_t)l * TS;

        // h = x ^ y*P2 ^ z*P3 ; for even x: h(x+1) = h(x)^1 (same aligned pair)
        const uint32_t bx = (uint32_t)ix;
        const uint32_t hy0 = (uint32_t)iy * P2, hy1 = hy0 + P2;
        const uint32_t hz0 = (uint32_t)iz * P3, hz1 = hz0 + P3;
        const uint32_t b00 = hy0 ^ hz0, b01 = hy0 ^ hz1;
        const uint32_t b10 = hy1 ^ hz0, b11 = hy1 ^ hz1;
        const uint32_t i00 = (bx ^ b00) & (TS - 1);
        const uint32_t i01 = (bx ^ b01) & (TS - 1);
        const uint32_t i10 = (bx ^ b10) & (TS - 1);
        const uint32_t i11 = (bx ^ b11) & (TS - 1);
        const float4* tbl4 = (const float4*)tbl;
        const float4 f00 = tbl4[i00 >> 1];
        const float4 f01 = tbl4[i01 >> 1];
        const float4 f10 = tbl4[i10 >> 1];
        const float4 f11 = tbl4[i11 >> 1];
        const float2 c0 = (i00 & 1) ? f4hi(f00) : f4lo(f00);
        const float2 c1 = (i01 & 1) ? f4hi(f01) : f4lo(f01);
        const float2 c2 = (i10 & 1) ? f4hi(f10) : f4lo(f10);
        const float2 c3 = (i11 & 1) ? f4hi(f11) : f4lo(f11);
        float2 c4, c5, c6, c7;
        if ((ix & 1) == 0) {
            c4 = (i00 & 1) ? f4lo(f00) : f4hi(f00);
            c5 = (i01 & 1) ? f4lo(f01) : f4hi(f01);
            c6 = (i10 & 1) ? f4lo(f10) : f4hi(f10);
            c7 = (i11 & 1) ? f4lo(f11) : f4hi(f11);
        } else {
            const uint32_t bx1 = bx + 1;
            c4 = tbl[(bx1 ^ b00) & (TS - 1)];
            c5 = tbl[(bx1 ^ b01) & (TS - 1)];
            c6 = tbl[(bx1 ^ b10) & (TS - 1)];
            c7 = tbl[(bx1 ^ b11) & (TS - 1)];
        }

        const float ux = 1.0f - wx, uy = 1.0f - wy, uz = 1.0f - wz;
        const float w0 = ux * uy * uz, w1 = ux * uy * wz;
        const float w2 = ux * wy * uz, w3 = ux * wy * wz;
        const float w4 = wx * uy * uz, w5 = wx * uy * wz;
        const float w6 = wx * wy * uz, w7 = wx * wy * wz;

        const float o0 = w0 * c0.x + w1 * c1.x + w2 * c2.x + w3 * c3.x +
                         w4 * c4.x + w5 * c5.x + w6 * c6.x + w7 * c7.x;
        const float o1 = w0 * c0.y + w1 * c1.y + w2 * c2.y + w3 * c3.y +
                         w4 * c4.y + w5 * c5.y + w6 * c6.y + w7 * c7.y;
        lds_put2(s_out, p, 2 * l, o0, o1);
    }

    __syncthreads();

    // ---- coalesced store: element g -> point g>>5, feature g&31 ----
    float* outb = out + (size_t)blockIdx.x * (256 * 32);
    const long long lim = (long long)n * 32 - (long long)blockIdx.x * (256 * 32);
#pragma unroll
    for (int r = 0; r < 32; ++r) {
        const int g = r * 256 + threadIdx.x;
        const int pp = g >> 5, f = g & 31;
        const float v = s_out[pp * 32 + (f ^ (pp & 31))];
        if (g < lim) outb[g] = v;
    }
}

extern "C" void kernel_launch(void* const* d_in, const int* in_sizes, int n_in,
                              void* d_out, int out_size, void* d_ws, size_t ws_size,
                              hipStream_t stream) {
    const float* x = (const float*)d_in[0];     // [N,3] f32
    const float* table = (const float*)d_in[1]; // [16,65536,2] f32
    float* out = (float*)d_out;                 // [N,32] f32
    const int n = in_sizes[0] / 3;
    const int block = 256;
    const int grid = (n + block - 1) / block;
    hashgrid_fwd<<<grid, block, 0, stream>>>(x, table, out, n);
}